// Round 4
// baseline (350.460 us; speedup 1.0000x reference)
//
#include <hip/hip_runtime.h>

#define NN   50000
#define NE   200000
#define INC  16
#define HIDC 32
#define EDGED 8
#define OUTC 32
#define MLPH 128
#define NACT 32

#define NPART 196   // ceil(NN / 256)

// ---- prep: transpose Wq1 [32,128] -> Wq1T [128,32] ----
__global__ __launch_bounds__(256) void transpose_wq1(const float* __restrict__ Wq1,
                                                     float* __restrict__ Wq1T) {
    int idx = blockIdx.x * blockDim.x + threadIdx.x;
    if (idx < OUTC * MLPH) {
        int k = idx / MLPH, m = idx % MLPH;        // Wq1[k][m]
        Wq1T[m * OUTC + k] = Wq1[idx];
    }
}

// ---- prep: transpose We [8][512] -> We_t [512][8] (contiguous d per (i,h)) ----
__global__ __launch_bounds__(256) void transpose_we(const float* __restrict__ We,
                                                    float* __restrict__ We_t) {
    int idx = blockIdx.x * blockDim.x + threadIdx.x;
    if (idx < EDGED * INC * HIDC) {
        int d = idx / (INC * HIDC), ih = idx % (INC * HIDC);
        We_t[ih * EDGED + d] = We[idx];
    }
}

// ---- degree histogram ----
__global__ __launch_bounds__(256) void hist_kernel(const int* __restrict__ edst,
                                                   int* __restrict__ deg) {
    int e = blockIdx.x * blockDim.x + threadIdx.x;
    if (e < NE) atomicAdd(&deg[edst[e]], 1);
}

// ---- scan pass 1: per-block sums ----
__global__ __launch_bounds__(256) void partial_kernel(const int* __restrict__ deg,
                                                      int* __restrict__ partials) {
    __shared__ int sm[256];
    int t = threadIdx.x, i = blockIdx.x * 256 + t;
    sm[t] = (i < NN) ? deg[i] : 0;
    __syncthreads();
    #pragma unroll
    for (int off = 128; off > 0; off >>= 1) {
        if (t < off) sm[t] += sm[t + off];
        __syncthreads();
    }
    if (t == 0) partials[blockIdx.x] = sm[0];
}

// ---- scan pass 2: exclusive scan of 196 partials ----
__global__ __launch_bounds__(256) void scan_partials_kernel(const int* __restrict__ partials,
                                                            int* __restrict__ poff) {
    __shared__ int sm[256];
    int t = threadIdx.x;
    sm[t] = (t < NPART) ? partials[t] : 0;
    __syncthreads();
    for (int off = 1; off < 256; off <<= 1) {
        int v = (t >= off) ? sm[t - off] : 0;
        __syncthreads();
        sm[t] += v;
        __syncthreads();
    }
    poff[t] = (t == 0) ? 0 : sm[t - 1];
}

// ---- scan pass 3: block-local scan + base -> row_off ----
__global__ __launch_bounds__(256) void rowoff_kernel(const int* __restrict__ deg,
                                                     const int* __restrict__ poff,
                                                     int* __restrict__ row_off) {
    __shared__ int sm[256];
    int t = threadIdx.x, i = blockIdx.x * 256 + t;
    int d = (i < NN) ? deg[i] : 0;
    sm[t] = d;
    __syncthreads();
    for (int off = 1; off < 256; off <<= 1) {
        int v = (t >= off) ? sm[t - off] : 0;
        __syncthreads();
        sm[t] += v;
        __syncthreads();
    }
    int excl = sm[t] - d + poff[blockIdx.x];
    if (i < NN) {
        row_off[i] = excl;
        if (i == NN - 1) row_off[NN] = excl + d;   // == NE
    }
}

// ---- edge kernel: one lane per edge; We_t gives contiguous 32B scalar loads ----
__global__ __launch_bounds__(256, 4) void edge_kernel(
    const float* __restrict__ x,
    const int*   __restrict__ esrc,
    const int*   __restrict__ edst,
    const float* __restrict__ ea,
    const float* __restrict__ We_t,   // [512][8]
    const float* __restrict__ be,
    const int*   __restrict__ row_off,
    int*         __restrict__ cursor,
    float*       __restrict__ sorted_msg)
{
    int e = blockIdx.x * blockDim.x + threadIdx.x;
    if (e >= NE) return;
    int src = esrc[e];
    int dst = edst[e];

    const float4* ea4 = reinterpret_cast<const float4*>(ea) + (size_t)e * 2;
    float4 ev0 = ea4[0], ev1 = ea4[1];
    float eav[8] = {ev0.x, ev0.y, ev0.z, ev0.w, ev1.x, ev1.y, ev1.z, ev1.w};

    float msg[HIDC];
    #pragma unroll
    for (int h = 0; h < HIDC; ++h) msg[h] = 0.f;

    const float4* x4 = reinterpret_cast<const float4*>(x) + (size_t)src * 4;

    for (int i4 = 0; i4 < 4; ++i4) {
        float4 xv = x4[i4];
        float xs[4] = {xv.x, xv.y, xv.z, xv.w};
        #pragma unroll
        for (int ii = 0; ii < 4; ++ii) {
            int i = i4 * 4 + ii;
            const float* wbase = We_t + i * (HIDC * EDGED);
            const float* becol = be + i * HIDC;
            float xi = xs[ii];
            #pragma unroll
            for (int h = 0; h < HIDC; ++h) {
                const float* wr = wbase + h * EDGED;   // 8 contiguous floats
                float w = becol[h];
                #pragma unroll
                for (int d = 0; d < EDGED; ++d)
                    w = fmaf(eav[d], wr[d], w);
                w = fmaxf(w, 0.f);
                msg[h] = fmaf(xi, w, msg[h]);
            }
        }
    }

    int pos = row_off[dst] + atomicAdd(&cursor[dst], 1);
    float4* mrow = reinterpret_cast<float4*>(sorted_msg) + (size_t)pos * 8;
    #pragma unroll
    for (int h4 = 0; h4 < 8; ++h4)
        mrow[h4] = make_float4(msg[h4 * 4 + 0], msg[h4 * 4 + 1],
                               msg[h4 * 4 + 2], msg[h4 * 4 + 3]);
}

// ---- node kernel: 4 lanes per node (quad). Lane l owns channel slice
//      [8l,8l+8) through gather/Wroot/LN/Wlin, m-rows j*4+l of q_head.
//      Cross-lane via __shfl_xor butterfly (quad-local). ----
__global__ __launch_bounds__(256, 4) void node_kernel(
    const float* __restrict__ x,
    const float* __restrict__ sorted_msg,
    const int*   __restrict__ row_off,
    const float* __restrict__ Wroot,   // [16][32]
    const float* __restrict__ bconv,
    const float* __restrict__ gamma,
    const float* __restrict__ beta,
    const float* __restrict__ Wlin,    // [32][32]
    const float* __restrict__ blin,
    const float* __restrict__ Wq1T,    // [128][32]
    const float* __restrict__ bq1,
    const float* __restrict__ Wq2,     // [128][32]
    const float* __restrict__ bq2,
    float* __restrict__ out)
{
    int tid = blockIdx.x * 256 + threadIdx.x;
    int n = tid >> 2;
    int l = tid & 3;
    if (n >= NN) return;

    // x[n] in full (broadcast across quad)
    float xs[INC];
    const float4* x4 = reinterpret_cast<const float4*>(x) + (size_t)n * 4;
    #pragma unroll
    for (int i4 = 0; i4 < 4; ++i4) {
        float4 v = x4[i4];
        xs[i4*4+0] = v.x; xs[i4*4+1] = v.y; xs[i4*4+2] = v.z; xs[i4*4+3] = v.w;
    }

    // h slice init = bconv slice
    float h8[8];
    {
        const float4* b4 = reinterpret_cast<const float4*>(bconv + l * 8);
        float4 b0 = b4[0], b1 = b4[1];
        h8[0]=b0.x; h8[1]=b0.y; h8[2]=b0.z; h8[3]=b0.w;
        h8[4]=b1.x; h8[5]=b1.y; h8[6]=b1.z; h8[7]=b1.w;
    }

    // gather: each lane sums its 8 channels of the node's message rows
    int start = row_off[n], end = row_off[n + 1];
    for (int k = start; k < end; ++k) {
        const float4* m4 = reinterpret_cast<const float4*>(
            sorted_msg + (size_t)k * HIDC + l * 8);
        float4 a = m4[0], b = m4[1];
        h8[0]+=a.x; h8[1]+=a.y; h8[2]+=a.z; h8[3]+=a.w;
        h8[4]+=b.x; h8[5]+=b.y; h8[6]+=b.z; h8[7]+=b.w;
    }

    // + x @ Wroot (column slice)
    #pragma unroll
    for (int i = 0; i < INC; ++i) {
        const float4* w4 = reinterpret_cast<const float4*>(Wroot + i * HIDC + l * 8);
        float4 a = w4[0], b = w4[1];
        float xi = xs[i];
        h8[0]=fmaf(xi,a.x,h8[0]); h8[1]=fmaf(xi,a.y,h8[1]);
        h8[2]=fmaf(xi,a.z,h8[2]); h8[3]=fmaf(xi,a.w,h8[3]);
        h8[4]=fmaf(xi,b.x,h8[4]); h8[5]=fmaf(xi,b.y,h8[5]);
        h8[6]=fmaf(xi,b.z,h8[6]); h8[7]=fmaf(xi,b.w,h8[7]);
    }

    // LayerNorm (two-pass, quad butterfly) + ReLU
    float s = ((h8[0]+h8[1])+(h8[2]+h8[3])) + ((h8[4]+h8[5])+(h8[6]+h8[7]));
    s += __shfl_xor(s, 1);
    s += __shfl_xor(s, 2);
    float mu = s * (1.f / HIDC);
    float v = 0.f;
    #pragma unroll
    for (int c = 0; c < 8; ++c) { float t = h8[c] - mu; v = fmaf(t, t, v); }
    v += __shfl_xor(v, 1);
    v += __shfl_xor(v, 2);
    float rstd = rsqrtf(v * (1.f / HIDC) + 1e-5f);
    {
        const float4* g4 = reinterpret_cast<const float4*>(gamma + l * 8);
        const float4* t4 = reinterpret_cast<const float4*>(beta + l * 8);
        float4 g0 = g4[0], g1 = g4[1], b0 = t4[0], b1 = t4[1];
        float gs[8] = {g0.x,g0.y,g0.z,g0.w,g1.x,g1.y,g1.z,g1.w};
        float bs[8] = {b0.x,b0.y,b0.z,b0.w,b1.x,b1.y,b1.z,b1.w};
        #pragma unroll
        for (int c = 0; c < 8; ++c)
            h8[c] = fmaxf(fmaf((h8[c] - mu) * rstd, gs[c], bs[c]), 0.f);
    }

    // feat partial: rows [8l,8l+8) of Wlin, then quad butterfly + blin
    float feat[OUTC];
    #pragma unroll
    for (int a = 0; a < OUTC; ++a) feat[a] = 0.f;
    #pragma unroll
    for (int k = 0; k < 8; ++k) {
        float hk = h8[k];
        const float4* w4 = reinterpret_cast<const float4*>(Wlin + (l * 8 + k) * OUTC);
        #pragma unroll
        for (int a4 = 0; a4 < 8; ++a4) {
            float4 w = w4[a4];
            feat[a4*4+0]=fmaf(hk,w.x,feat[a4*4+0]);
            feat[a4*4+1]=fmaf(hk,w.y,feat[a4*4+1]);
            feat[a4*4+2]=fmaf(hk,w.z,feat[a4*4+2]);
            feat[a4*4+3]=fmaf(hk,w.w,feat[a4*4+3]);
        }
    }
    #pragma unroll
    for (int a = 0; a < OUTC; ++a) {
        feat[a] += __shfl_xor(feat[a], 1);
        feat[a] += __shfl_xor(feat[a], 2);
    }
    {
        const float4* bl4 = reinterpret_cast<const float4*>(blin);
        #pragma unroll
        for (int a4 = 0; a4 < 8; ++a4) {
            float4 b = bl4[a4];
            feat[a4*4+0]+=b.x; feat[a4*4+1]+=b.y; feat[a4*4+2]+=b.z; feat[a4*4+3]+=b.w;
        }
    }

    // q_head: lane handles m = j*4 + l (quad covers 4 consecutive rows)
    float q[NACT];
    #pragma unroll
    for (int a = 0; a < NACT; ++a) q[a] = 0.f;
    #pragma unroll 2
    for (int j = 0; j < MLPH / 4; ++j) {
        int m = j * 4 + l;
        float t = bq1[m];
        const float4* w1 = reinterpret_cast<const float4*>(Wq1T + m * OUTC);
        float t0 = 0.f, t1 = 0.f, t2 = 0.f, t3 = 0.f;
        #pragma unroll
        for (int k4 = 0; k4 < 8; ++k4) {
            float4 w = w1[k4];
            t0 = fmaf(feat[k4*4+0], w.x, t0);
            t1 = fmaf(feat[k4*4+1], w.y, t1);
            t2 = fmaf(feat[k4*4+2], w.z, t2);
            t3 = fmaf(feat[k4*4+3], w.w, t3);
        }
        t += (t0 + t1) + (t2 + t3);
        t = fmaxf(t, 0.f);
        const float4* w2 = reinterpret_cast<const float4*>(Wq2 + m * NACT);
        #pragma unroll
        for (int a4 = 0; a4 < 8; ++a4) {
            float4 w = w2[a4];
            q[a4*4+0]=fmaf(t,w.x,q[a4*4+0]);
            q[a4*4+1]=fmaf(t,w.y,q[a4*4+1]);
            q[a4*4+2]=fmaf(t,w.z,q[a4*4+2]);
            q[a4*4+3]=fmaf(t,w.w,q[a4*4+3]);
        }
    }
    #pragma unroll
    for (int a = 0; a < NACT; ++a) {
        q[a] += __shfl_xor(q[a], 1);
        q[a] += __shfl_xor(q[a], 2);
    }
    {
        const float4* b4 = reinterpret_cast<const float4*>(bq2);
        #pragma unroll
        for (int a4 = 0; a4 < 8; ++a4) {
            float4 b = b4[a4];
            q[a4*4+0]+=b.x; q[a4*4+1]+=b.y; q[a4*4+2]+=b.z; q[a4*4+3]+=b.w;
        }
    }

    // lane writes its 8 outputs; compile-time q indices per case (no scratch)
    float4* o4 = reinterpret_cast<float4*>(out + (size_t)n * NACT + l * 8);
    switch (l) {
    case 0:
        o4[0] = make_float4(q[0],q[1],q[2],q[3]);
        o4[1] = make_float4(q[4],q[5],q[6],q[7]);
        break;
    case 1:
        o4[0] = make_float4(q[8],q[9],q[10],q[11]);
        o4[1] = make_float4(q[12],q[13],q[14],q[15]);
        break;
    case 2:
        o4[0] = make_float4(q[16],q[17],q[18],q[19]);
        o4[1] = make_float4(q[20],q[21],q[22],q[23]);
        break;
    default:
        o4[0] = make_float4(q[24],q[25],q[26],q[27]);
        o4[1] = make_float4(q[28],q[29],q[30],q[31]);
        break;
    }
}

extern "C" void kernel_launch(void* const* d_in, const int* in_sizes, int n_in,
                              void* d_out, int out_size, void* d_ws, size_t ws_size,
                              hipStream_t stream) {
    const float* x     = (const float*)d_in[0];
    const int*   esrc  = (const int*)d_in[1];
    const int*   edst  = (const int*)d_in[2];
    const float* ea    = (const float*)d_in[3];
    const float* We    = (const float*)d_in[4];
    const float* be    = (const float*)d_in[5];
    const float* Wroot = (const float*)d_in[6];
    const float* bconv = (const float*)d_in[7];
    const float* gamma = (const float*)d_in[8];
    const float* beta  = (const float*)d_in[9];
    const float* Wlin  = (const float*)d_in[10];
    const float* blin  = (const float*)d_in[11];
    const float* Wq1   = (const float*)d_in[12];
    const float* bq1   = (const float*)d_in[13];
    const float* Wq2   = (const float*)d_in[14];
    const float* bq2   = (const float*)d_in[15];
    float* out = (float*)d_out;

    // workspace layout
    char* ws = (char*)d_ws;
    float* Wq1T       = (float*)(ws + 0);        //  16 KB
    float* We_t       = (float*)(ws + 16384);    //  16 KB
    int*   deg        = (int*)(ws + 32768);      // 200704 B
    int*   cursor     = (int*)(ws + 233472);     // 200704 B
    int*   row_off    = (int*)(ws + 434176);     // 200708 B (pad to 201728)
    int*   partials   = (int*)(ws + 635904);     // 1 KB
    int*   poff       = (int*)(ws + 636928);     // 1 KB
    float* sorted_msg = (float*)(ws + 637952);   // 25.6 MB

    hipMemsetAsync(deg, 0, 2 * 200704, stream);  // deg + cursor (adjacent)

    transpose_wq1<<<16, 256, 0, stream>>>(Wq1, Wq1T);
    transpose_we<<<16, 256, 0, stream>>>(We, We_t);
    hist_kernel<<<(NE + 255) / 256, 256, 0, stream>>>(edst, deg);
    partial_kernel<<<NPART, 256, 0, stream>>>(deg, partials);
    scan_partials_kernel<<<1, 256, 0, stream>>>(partials, poff);
    rowoff_kernel<<<NPART, 256, 0, stream>>>(deg, poff, row_off);
    edge_kernel<<<(NE + 255) / 256, 256, 0, stream>>>(x, esrc, edst, ea, We_t, be,
                                                      row_off, cursor, sorted_msg);
    node_kernel<<<(NN * 4 + 255) / 256, 256, 0, stream>>>(x, sorted_msg, row_off,
                                                          Wroot, bconv, gamma, beta,
                                                          Wlin, blin, Wq1T, bq1, Wq2, bq2, out);
}

// Round 5
// 182.171 us; speedup vs baseline: 1.9238x; 1.9238x over previous
//
#include <hip/hip_runtime.h>

#define NN   50000
#define NE   200000
#define INC  16
#define HIDC 32
#define EDGED 8
#define OUTC 32
#define MLPH 128
#define NACT 32

#define NPART 196   // ceil(NN / 256)

// ---- prep: transpose Wq1 [32,128] -> Wq1T [128,32] ----
__global__ __launch_bounds__(256) void transpose_wq1(const float* __restrict__ Wq1,
                                                     float* __restrict__ Wq1T) {
    int idx = blockIdx.x * blockDim.x + threadIdx.x;
    if (idx < OUTC * MLPH) {
        int k = idx / MLPH, m = idx % MLPH;        // Wq1[k][m]
        Wq1T[m * OUTC + k] = Wq1[idx];
    }
}

// ---- prep: transpose We [8][512] -> We_t [512][8] ----
__global__ __launch_bounds__(256) void transpose_we(const float* __restrict__ We,
                                                    float* __restrict__ We_t) {
    int idx = blockIdx.x * blockDim.x + threadIdx.x;
    if (idx < EDGED * INC * HIDC) {
        int d = idx / (INC * HIDC), ih = idx % (INC * HIDC);
        We_t[ih * EDGED + d] = We[idx];
    }
}

// ---- degree histogram ----
__global__ __launch_bounds__(256) void hist_kernel(const int* __restrict__ edst,
                                                   int* __restrict__ deg) {
    int e = blockIdx.x * blockDim.x + threadIdx.x;
    if (e < NE) atomicAdd(&deg[edst[e]], 1);
}

// ---- scan pass 1: per-block sums ----
__global__ __launch_bounds__(256) void partial_kernel(const int* __restrict__ deg,
                                                      int* __restrict__ partials) {
    __shared__ int sm[256];
    int t = threadIdx.x, i = blockIdx.x * 256 + t;
    sm[t] = (i < NN) ? deg[i] : 0;
    __syncthreads();
    #pragma unroll
    for (int off = 128; off > 0; off >>= 1) {
        if (t < off) sm[t] += sm[t + off];
        __syncthreads();
    }
    if (t == 0) partials[blockIdx.x] = sm[0];
}

// ---- scan pass 2: exclusive scan of 196 partials ----
__global__ __launch_bounds__(256) void scan_partials_kernel(const int* __restrict__ partials,
                                                            int* __restrict__ poff) {
    __shared__ int sm[256];
    int t = threadIdx.x;
    sm[t] = (t < NPART) ? partials[t] : 0;
    __syncthreads();
    for (int off = 1; off < 256; off <<= 1) {
        int v = (t >= off) ? sm[t - off] : 0;
        __syncthreads();
        sm[t] += v;
        __syncthreads();
    }
    poff[t] = (t == 0) ? 0 : sm[t - 1];
}

// ---- scan pass 3: block-local scan + base -> row_off ----
__global__ __launch_bounds__(256) void rowoff_kernel(const int* __restrict__ deg,
                                                     const int* __restrict__ poff,
                                                     int* __restrict__ row_off) {
    __shared__ int sm[256];
    int t = threadIdx.x, i = blockIdx.x * 256 + t;
    int d = (i < NN) ? deg[i] : 0;
    sm[t] = d;
    __syncthreads();
    for (int off = 1; off < 256; off <<= 1) {
        int v = (t >= off) ? sm[t - off] : 0;
        __syncthreads();
        sm[t] += v;
        __syncthreads();
    }
    int excl = sm[t] - d + poff[blockIdx.x];
    if (i < NN) {
        row_off[i] = excl;
        if (i == NN - 1) row_off[NN] = excl + d;   // == NE
    }
}

// ---- edge kernel: one lane per edge; We_t gives contiguous 32B uniform loads ----
__global__ __launch_bounds__(256, 4) void edge_kernel(
    const float* __restrict__ x,
    const int*   __restrict__ esrc,
    const int*   __restrict__ edst,
    const float* __restrict__ ea,
    const float* __restrict__ We_t,   // [512][8]
    const float* __restrict__ be,
    const int*   __restrict__ row_off,
    int*         __restrict__ cursor,
    float*       __restrict__ sorted_msg)
{
    int e = blockIdx.x * blockDim.x + threadIdx.x;
    if (e >= NE) return;
    int src = esrc[e];
    int dst = edst[e];

    const float4* ea4 = reinterpret_cast<const float4*>(ea) + (size_t)e * 2;
    float4 ev0 = ea4[0], ev1 = ea4[1];
    float eav[8] = {ev0.x, ev0.y, ev0.z, ev0.w, ev1.x, ev1.y, ev1.z, ev1.w};

    float msg[HIDC];
    #pragma unroll
    for (int h = 0; h < HIDC; ++h) msg[h] = 0.f;

    const float4* x4 = reinterpret_cast<const float4*>(x) + (size_t)src * 4;

    for (int i4 = 0; i4 < 4; ++i4) {
        float4 xv = x4[i4];
        float xs[4] = {xv.x, xv.y, xv.z, xv.w};
        #pragma unroll
        for (int ii = 0; ii < 4; ++ii) {
            int i = i4 * 4 + ii;
            const float* wbase = We_t + i * (HIDC * EDGED);
            const float* becol = be + i * HIDC;
            float xi = xs[ii];
            #pragma unroll
            for (int h = 0; h < HIDC; ++h) {
                const float* wr = wbase + h * EDGED;
                float w = becol[h];
                #pragma unroll
                for (int d = 0; d < EDGED; ++d)
                    w = fmaf(eav[d], wr[d], w);
                w = fmaxf(w, 0.f);
                msg[h] = fmaf(xi, w, msg[h]);
            }
        }
    }

    int pos = row_off[dst] + atomicAdd(&cursor[dst], 1);
    float4* mrow = reinterpret_cast<float4*>(sorted_msg) + (size_t)pos * 8;
    #pragma unroll
    for (int h4 = 0; h4 < 8; ++h4)
        mrow[h4] = make_float4(msg[h4 * 4 + 0], msg[h4 * 4 + 1],
                               msg[h4 * 4 + 2], msg[h4 * 4 + 3]);
}

// ---- feat kernel: 4 lanes/node. Lane l owns channels [8l,8l+8).
//      gather + Wroot slice -> LN (4 scalar quad-shuffles) -> broadcast h
//      (32 width-4 shuffles, compile-time) -> lane's 8 feat cols (complete). ----
__global__ __launch_bounds__(256, 4) void feat_kernel(
    const float* __restrict__ x,
    const float* __restrict__ sorted_msg,
    const int*   __restrict__ row_off,
    const float* __restrict__ Wroot,   // [16][32]
    const float* __restrict__ bconv,
    const float* __restrict__ gamma,
    const float* __restrict__ beta,
    const float* __restrict__ Wlin,    // [32][32]
    const float* __restrict__ blin,
    float* __restrict__ feat)          // [NN][32]
{
    int tid = blockIdx.x * 256 + threadIdx.x;
    int n = tid >> 2;
    int l = tid & 3;
    if (n >= NN) return;
    int c0 = l * 8;

    // h slice init = bconv slice
    float h8[8];
    {
        const float4* b4 = reinterpret_cast<const float4*>(bconv + c0);
        float4 a = b4[0], b = b4[1];
        h8[0]=a.x; h8[1]=a.y; h8[2]=a.z; h8[3]=a.w;
        h8[4]=b.x; h8[5]=b.y; h8[6]=b.z; h8[7]=b.w;
    }

    // gather own channel slice of the node's contiguous message rows
    int start = row_off[n], end = row_off[n + 1];
    for (int k = start; k < end; ++k) {
        const float4* m4 = reinterpret_cast<const float4*>(
            sorted_msg + (size_t)k * HIDC + c0);
        float4 a = m4[0], b = m4[1];
        h8[0]+=a.x; h8[1]+=a.y; h8[2]+=a.z; h8[3]+=a.w;
        h8[4]+=b.x; h8[5]+=b.y; h8[6]+=b.z; h8[7]+=b.w;
    }

    // + x @ Wroot (column slice)
    const float4* x4 = reinterpret_cast<const float4*>(x) + (size_t)n * 4;
    #pragma unroll
    for (int i4 = 0; i4 < 4; ++i4) {
        float4 xv = x4[i4];
        float xsub[4] = {xv.x, xv.y, xv.z, xv.w};
        #pragma unroll
        for (int ii = 0; ii < 4; ++ii) {
            const float4* w4 = reinterpret_cast<const float4*>(
                Wroot + (i4 * 4 + ii) * HIDC + c0);
            float4 a = w4[0], b = w4[1];
            float xi = xsub[ii];
            h8[0]=fmaf(xi,a.x,h8[0]); h8[1]=fmaf(xi,a.y,h8[1]);
            h8[2]=fmaf(xi,a.z,h8[2]); h8[3]=fmaf(xi,a.w,h8[3]);
            h8[4]=fmaf(xi,b.x,h8[4]); h8[5]=fmaf(xi,b.y,h8[5]);
            h8[6]=fmaf(xi,b.z,h8[6]); h8[7]=fmaf(xi,b.w,h8[7]);
        }
    }

    // LayerNorm (two-pass, quad butterfly on scalars) + ReLU
    float s = ((h8[0]+h8[1])+(h8[2]+h8[3])) + ((h8[4]+h8[5])+(h8[6]+h8[7]));
    s += __shfl_xor(s, 1);
    s += __shfl_xor(s, 2);
    float mu = s * (1.f / HIDC);
    float v = 0.f;
    #pragma unroll
    for (int c = 0; c < 8; ++c) { float t = h8[c] - mu; v = fmaf(t, t, v); }
    v += __shfl_xor(v, 1);
    v += __shfl_xor(v, 2);
    float rstd = rsqrtf(v * (1.f / HIDC) + 1e-5f);
    {
        const float4* g4 = reinterpret_cast<const float4*>(gamma + c0);
        const float4* t4 = reinterpret_cast<const float4*>(beta + c0);
        float4 g0 = g4[0], g1 = g4[1], b0 = t4[0], b1 = t4[1];
        float gs[8] = {g0.x,g0.y,g0.z,g0.w,g1.x,g1.y,g1.z,g1.w};
        float bs[8] = {b0.x,b0.y,b0.z,b0.w,b1.x,b1.y,b1.z,b1.w};
        #pragma unroll
        for (int c = 0; c < 8; ++c)
            h8[c] = fmaxf(fmaf((h8[c] - mu) * rstd, gs[c], bs[c]), 0.f);
    }

    // feat cols [c0,c0+8): broadcast each h[k] via width-4 shuffle (compile-time reg)
    float f8[8];
    {
        const float4* bl4 = reinterpret_cast<const float4*>(blin + c0);
        float4 a = bl4[0], b = bl4[1];
        f8[0]=a.x; f8[1]=a.y; f8[2]=a.z; f8[3]=a.w;
        f8[4]=b.x; f8[5]=b.y; f8[6]=b.z; f8[7]=b.w;
    }
    #pragma unroll
    for (int src = 0; src < 4; ++src) {
        #pragma unroll
        for (int c = 0; c < 8; ++c) {
            float hv = __shfl(h8[c], src, 4);      // h[src*8 + c]
            const float4* w4 = reinterpret_cast<const float4*>(
                Wlin + (src * 8 + c) * OUTC + c0);
            float4 a = w4[0], b = w4[1];
            f8[0]=fmaf(hv,a.x,f8[0]); f8[1]=fmaf(hv,a.y,f8[1]);
            f8[2]=fmaf(hv,a.z,f8[2]); f8[3]=fmaf(hv,a.w,f8[3]);
            f8[4]=fmaf(hv,b.x,f8[4]); f8[5]=fmaf(hv,b.y,f8[5]);
            f8[6]=fmaf(hv,b.z,f8[6]); f8[7]=fmaf(hv,b.w,f8[7]);
        }
    }

    float4* o4 = reinterpret_cast<float4*>(feat + (size_t)n * OUTC + c0);
    o4[0] = make_float4(f8[0], f8[1], f8[2], f8[3]);
    o4[1] = make_float4(f8[4], f8[5], f8[6], f8[7]);
}

// ---- q_head kernel: 4 lanes/node. Lane owns q cols [8l,8l+8); feat[32]
//      replicated per lane; act on-the-fly; ZERO shuffles; complete sums. ----
__global__ __launch_bounds__(256, 4) void qhead_kernel(
    const float* __restrict__ feat,    // [NN][32]
    const float* __restrict__ Wq1T,    // [128][32]
    const float* __restrict__ bq1,
    const float* __restrict__ Wq2,     // [128][32]
    const float* __restrict__ bq2,
    float* __restrict__ out)
{
    int tid = blockIdx.x * 256 + threadIdx.x;
    int n = tid >> 2;
    int l = tid & 3;
    if (n >= NN) return;
    int c0 = l * 8;

    float f[OUTC];
    const float4* f4 = reinterpret_cast<const float4*>(feat + (size_t)n * OUTC);
    #pragma unroll
    for (int i = 0; i < 8; ++i) {
        float4 v = f4[i];
        f[i*4+0]=v.x; f[i*4+1]=v.y; f[i*4+2]=v.z; f[i*4+3]=v.w;
    }

    float q8[8];
    {
        const float4* b4 = reinterpret_cast<const float4*>(bq2 + c0);
        float4 a = b4[0], b = b4[1];
        q8[0]=a.x; q8[1]=a.y; q8[2]=a.z; q8[3]=a.w;
        q8[4]=b.x; q8[5]=b.y; q8[6]=b.z; q8[7]=b.w;
    }

    #pragma unroll 4
    for (int m = 0; m < MLPH; ++m) {
        const float4* w1 = reinterpret_cast<const float4*>(Wq1T + m * OUTC);
        float t0 = 0.f, t1 = 0.f, t2 = 0.f, t3 = 0.f;
        #pragma unroll
        for (int k4 = 0; k4 < 8; ++k4) {
            float4 w = w1[k4];
            t0 = fmaf(f[k4*4+0], w.x, t0);
            t1 = fmaf(f[k4*4+1], w.y, t1);
            t2 = fmaf(f[k4*4+2], w.z, t2);
            t3 = fmaf(f[k4*4+3], w.w, t3);
        }
        float t = fmaxf(bq1[m] + ((t0 + t1) + (t2 + t3)), 0.f);
        const float4* w2 = reinterpret_cast<const float4*>(Wq2 + m * NACT + c0);
        float4 wa = w2[0], wb = w2[1];
        q8[0]=fmaf(t,wa.x,q8[0]); q8[1]=fmaf(t,wa.y,q8[1]);
        q8[2]=fmaf(t,wa.z,q8[2]); q8[3]=fmaf(t,wa.w,q8[3]);
        q8[4]=fmaf(t,wb.x,q8[4]); q8[5]=fmaf(t,wb.y,q8[5]);
        q8[6]=fmaf(t,wb.z,q8[6]); q8[7]=fmaf(t,wb.w,q8[7]);
    }

    float4* o4 = reinterpret_cast<float4*>(out + (size_t)n * NACT + c0);
    o4[0] = make_float4(q8[0], q8[1], q8[2], q8[3]);
    o4[1] = make_float4(q8[4], q8[5], q8[6], q8[7]);
}

extern "C" void kernel_launch(void* const* d_in, const int* in_sizes, int n_in,
                              void* d_out, int out_size, void* d_ws, size_t ws_size,
                              hipStream_t stream) {
    const float* x     = (const float*)d_in[0];
    const int*   esrc  = (const int*)d_in[1];
    const int*   edst  = (const int*)d_in[2];
    const float* ea    = (const float*)d_in[3];
    const float* We    = (const float*)d_in[4];
    const float* be    = (const float*)d_in[5];
    const float* Wroot = (const float*)d_in[6];
    const float* bconv = (const float*)d_in[7];
    const float* gamma = (const float*)d_in[8];
    const float* beta  = (const float*)d_in[9];
    const float* Wlin  = (const float*)d_in[10];
    const float* blin  = (const float*)d_in[11];
    const float* Wq1   = (const float*)d_in[12];
    const float* bq1   = (const float*)d_in[13];
    const float* Wq2   = (const float*)d_in[14];
    const float* bq2   = (const float*)d_in[15];
    float* out = (float*)d_out;

    // workspace layout
    char* ws = (char*)d_ws;
    float* Wq1T       = (float*)(ws + 0);         //  16 KB
    float* We_t       = (float*)(ws + 16384);     //  16 KB
    int*   deg        = (int*)(ws + 32768);       // 200704 B
    int*   cursor     = (int*)(ws + 233472);      // 200704 B
    int*   row_off    = (int*)(ws + 434176);      // 201728 B
    int*   partials   = (int*)(ws + 635904);      // 1 KB
    int*   poff       = (int*)(ws + 636928);      // 1 KB
    float* sorted_msg = (float*)(ws + 637952);    // 25.6 MB
    float* featb      = (float*)(ws + 637952 + (size_t)NE * HIDC * 4); // 6.4 MB

    hipMemsetAsync(deg, 0, 2 * 200704, stream);   // deg + cursor (adjacent)

    transpose_wq1<<<16, 256, 0, stream>>>(Wq1, Wq1T);
    transpose_we<<<16, 256, 0, stream>>>(We, We_t);
    hist_kernel<<<(NE + 255) / 256, 256, 0, stream>>>(edst, deg);
    partial_kernel<<<NPART, 256, 0, stream>>>(deg, partials);
    scan_partials_kernel<<<1, 256, 0, stream>>>(partials, poff);
    rowoff_kernel<<<NPART, 256, 0, stream>>>(deg, poff, row_off);
    edge_kernel<<<(NE + 255) / 256, 256, 0, stream>>>(x, esrc, edst, ea, We_t, be,
                                                      row_off, cursor, sorted_msg);
    feat_kernel<<<(NN * 4 + 255) / 256, 256, 0, stream>>>(x, sorted_msg, row_off,
                                                          Wroot, bconv, gamma, beta,
                                                          Wlin, blin, featb);
    qhead_kernel<<<(NN * 4 + 255) / 256, 256, 0, stream>>>(featb, Wq1T, bq1,
                                                           Wq2, bq2, out);
}

// Round 6
// 151.766 us; speedup vs baseline: 2.3092x; 1.2003x over previous
//
#include <hip/hip_runtime.h>

#define NN   50000
#define NE   200000
#define INC  16
#define HIDC 32
#define EDGED 8
#define OUTC 32
#define MLPH 128
#define NACT 32

#define NPART 196   // ceil(NN / 256)

// ---- prep: transpose We [8][512] -> We_t [512][8] ----
__global__ __launch_bounds__(256) void transpose_we(const float* __restrict__ We,
                                                    float* __restrict__ We_t) {
    int idx = blockIdx.x * blockDim.x + threadIdx.x;
    if (idx < EDGED * INC * HIDC) {
        int d = idx / (INC * HIDC), ih = idx % (INC * HIDC);
        We_t[ih * EDGED + d] = We[idx];
    }
}

// ---- degree histogram ----
__global__ __launch_bounds__(256) void hist_kernel(const int* __restrict__ edst,
                                                   int* __restrict__ deg) {
    int e = blockIdx.x * blockDim.x + threadIdx.x;
    if (e < NE) atomicAdd(&deg[edst[e]], 1);
}

// ---- scan pass 1: per-block sums ----
__global__ __launch_bounds__(256) void partial_kernel(const int* __restrict__ deg,
                                                      int* __restrict__ partials) {
    __shared__ int sm[256];
    int t = threadIdx.x, i = blockIdx.x * 256 + t;
    sm[t] = (i < NN) ? deg[i] : 0;
    __syncthreads();
    #pragma unroll
    for (int off = 128; off > 0; off >>= 1) {
        if (t < off) sm[t] += sm[t + off];
        __syncthreads();
    }
    if (t == 0) partials[blockIdx.x] = sm[0];
}

// ---- scan pass 2: exclusive scan of 196 partials ----
__global__ __launch_bounds__(256) void scan_partials_kernel(const int* __restrict__ partials,
                                                            int* __restrict__ poff) {
    __shared__ int sm[256];
    int t = threadIdx.x;
    sm[t] = (t < NPART) ? partials[t] : 0;
    __syncthreads();
    for (int off = 1; off < 256; off <<= 1) {
        int v = (t >= off) ? sm[t - off] : 0;
        __syncthreads();
        sm[t] += v;
        __syncthreads();
    }
    poff[t] = (t == 0) ? 0 : sm[t - 1];
}

// ---- scan pass 3: block-local scan + base -> row_off ----
__global__ __launch_bounds__(256) void rowoff_kernel(const int* __restrict__ deg,
                                                     const int* __restrict__ poff,
                                                     int* __restrict__ row_off) {
    __shared__ int sm[256];
    int t = threadIdx.x, i = blockIdx.x * 256 + t;
    int d = (i < NN) ? deg[i] : 0;
    sm[t] = d;
    __syncthreads();
    for (int off = 1; off < 256; off <<= 1) {
        int v = (t >= off) ? sm[t - off] : 0;
        __syncthreads();
        sm[t] += v;
        __syncthreads();
    }
    int excl = sm[t] - d + poff[blockIdx.x];
    if (i < NN) {
        row_off[i] = excl;
        if (i == NN - 1) row_off[NN] = excl + d;   // == NE
    }
}

// ---- edge kernel: one lane per edge; We_t gives contiguous 32B uniform loads ----
__global__ __launch_bounds__(256, 4) void edge_kernel(
    const float* __restrict__ x,
    const int*   __restrict__ esrc,
    const int*   __restrict__ edst,
    const float* __restrict__ ea,
    const float* __restrict__ We_t,   // [512][8]
    const float* __restrict__ be,
    const int*   __restrict__ row_off,
    int*         __restrict__ cursor,
    float*       __restrict__ sorted_msg)
{
    int e = blockIdx.x * blockDim.x + threadIdx.x;
    if (e >= NE) return;
    int src = esrc[e];
    int dst = edst[e];

    const float4* ea4 = reinterpret_cast<const float4*>(ea) + (size_t)e * 2;
    float4 ev0 = ea4[0], ev1 = ea4[1];
    float eav[8] = {ev0.x, ev0.y, ev0.z, ev0.w, ev1.x, ev1.y, ev1.z, ev1.w};

    float msg[HIDC];
    #pragma unroll
    for (int h = 0; h < HIDC; ++h) msg[h] = 0.f;

    const float4* x4 = reinterpret_cast<const float4*>(x) + (size_t)src * 4;

    for (int i4 = 0; i4 < 4; ++i4) {
        float4 xv = x4[i4];
        float xs[4] = {xv.x, xv.y, xv.z, xv.w};
        #pragma unroll
        for (int ii = 0; ii < 4; ++ii) {
            int i = i4 * 4 + ii;
            const float* wbase = We_t + i * (HIDC * EDGED);
            const float* becol = be + i * HIDC;
            float xi = xs[ii];
            #pragma unroll
            for (int h = 0; h < HIDC; ++h) {
                const float* wr = wbase + h * EDGED;
                float w = becol[h];
                #pragma unroll
                for (int d = 0; d < EDGED; ++d)
                    w = fmaf(eav[d], wr[d], w);
                w = fmaxf(w, 0.f);
                msg[h] = fmaf(xi, w, msg[h]);
            }
        }
    }

    int pos = row_off[dst] + atomicAdd(&cursor[dst], 1);
    float4* mrow = reinterpret_cast<float4*>(sorted_msg) + (size_t)pos * 8;
    #pragma unroll
    for (int h4 = 0; h4 < 8; ++h4)
        mrow[h4] = make_float4(msg[h4 * 4 + 0], msg[h4 * 4 + 1],
                               msg[h4 * 4 + 2], msg[h4 * 4 + 3]);
}

// ---- fused node kernel: 1 thread per node. ALL weight reads are wave-uniform
//      -> s_load through scalar cache; body is a near-pure v_fmac stream with
//      32 independent acc chains (full ILP, no per-lane weight VMEM).
//      gather + Wroot + LN + Wlin + q_head in one pass, no featb round-trip. ----
__global__ __launch_bounds__(64, 1) void node_fused_kernel(
    const float* __restrict__ x,
    const float* __restrict__ sorted_msg,
    const int*   __restrict__ row_off,
    const float* __restrict__ Wroot,   // [16][32]
    const float* __restrict__ bconv,
    const float* __restrict__ gamma,
    const float* __restrict__ beta,
    const float* __restrict__ Wlin,    // [32][32]
    const float* __restrict__ blin,
    const float* __restrict__ Wq1,     // [32][128]  (original layout)
    const float* __restrict__ bq1,
    const float* __restrict__ Wq2,     // [128][32]
    const float* __restrict__ bq2,
    float* __restrict__ out)
{
    int n = blockIdx.x * 64 + threadIdx.x;
    if (n >= NN) return;

    // ---- h = bconv + sum(msg rows) + x @ Wroot ----
    float h[HIDC];
    #pragma unroll
    for (int c = 0; c < HIDC; ++c) h[c] = bconv[c];

    int start = row_off[n], end = row_off[n + 1];
    for (int k = start; k < end; ++k) {
        const float4* m4 = reinterpret_cast<const float4*>(sorted_msg) + (size_t)k * 8;
        #pragma unroll
        for (int c4 = 0; c4 < 8; ++c4) {
            float4 m = m4[c4];
            h[c4 * 4 + 0] += m.x;
            h[c4 * 4 + 1] += m.y;
            h[c4 * 4 + 2] += m.z;
            h[c4 * 4 + 3] += m.w;
        }
    }

    const float4* x4 = reinterpret_cast<const float4*>(x) + (size_t)n * 4;
    #pragma unroll
    for (int i4 = 0; i4 < 4; ++i4) {
        float4 xv = x4[i4];
        float xs[4] = {xv.x, xv.y, xv.z, xv.w};
        #pragma unroll
        for (int ii = 0; ii < 4; ++ii) {
            const float* wr = Wroot + (i4 * 4 + ii) * HIDC;   // uniform
            float xi = xs[ii];
            #pragma unroll
            for (int c = 0; c < HIDC; ++c)
                h[c] = fmaf(xi, wr[c], h[c]);
        }
    }

    // ---- LayerNorm (two-pass) + ReLU, fully in-thread ----
    float mu = 0.f;
    #pragma unroll
    for (int c = 0; c < HIDC; ++c) mu += h[c];
    mu *= (1.f / HIDC);
    float var = 0.f;
    #pragma unroll
    for (int c = 0; c < HIDC; ++c) { float t = h[c] - mu; var = fmaf(t, t, var); }
    var *= (1.f / HIDC);
    float rstd = rsqrtf(var + 1e-5f);
    #pragma unroll
    for (int c = 0; c < HIDC; ++c)
        h[c] = fmaxf(fmaf((h[c] - mu) * rstd, gamma[c], beta[c]), 0.f);

    // ---- feat = h @ Wlin + blin (uniform weight rows) ----
    float f[OUTC];
    #pragma unroll
    for (int a = 0; a < OUTC; ++a) f[a] = blin[a];
    #pragma unroll
    for (int k = 0; k < HIDC; ++k) {
        float hk = h[k];
        const float* wr = Wlin + k * OUTC;                    // uniform
        #pragma unroll
        for (int a = 0; a < OUTC; ++a)
            f[a] = fmaf(hk, wr[a], f[a]);
    }

    // ---- q_head in 4 m-chunks of 32 (chunk loop rolled: code stays I$-sized;
    //      inner k/j fully unrolled: compile-time register indices) ----
    float q[NACT];
    #pragma unroll
    for (int a = 0; a < NACT; ++a) q[a] = bq2[a];

    for (int c = 0; c < 4; ++c) {
        const float* w1c = Wq1 + c * 32;          // column block: [k][c*32+j]
        const float* b1c = bq1 + c * 32;
        const float* w2c = Wq2 + c * 32 * NACT;   // rows c*32 .. c*32+32

        float acc[32];
        #pragma unroll
        for (int j = 0; j < 32; ++j) acc[j] = b1c[j];

        #pragma unroll
        for (int k = 0; k < 32; ++k) {
            float fk = f[k];
            const float* wr = w1c + k * MLPH;     // 128B contiguous, uniform
            #pragma unroll
            for (int j = 0; j < 32; ++j)
                acc[j] = fmaf(fk, wr[j], acc[j]);
        }

        #pragma unroll
        for (int j = 0; j < 32; ++j) {
            float t = fmaxf(acc[j], 0.f);
            const float* wr = w2c + j * NACT;     // 128B contiguous, uniform
            #pragma unroll
            for (int a = 0; a < NACT; ++a)
                q[a] = fmaf(t, wr[a], q[a]);
        }
    }

    float4* o4 = reinterpret_cast<float4*>(out) + (size_t)n * 8;
    #pragma unroll
    for (int a4 = 0; a4 < 8; ++a4)
        o4[a4] = make_float4(q[a4 * 4 + 0], q[a4 * 4 + 1], q[a4 * 4 + 2], q[a4 * 4 + 3]);
}

extern "C" void kernel_launch(void* const* d_in, const int* in_sizes, int n_in,
                              void* d_out, int out_size, void* d_ws, size_t ws_size,
                              hipStream_t stream) {
    const float* x     = (const float*)d_in[0];
    const int*   esrc  = (const int*)d_in[1];
    const int*   edst  = (const int*)d_in[2];
    const float* ea    = (const float*)d_in[3];
    const float* We    = (const float*)d_in[4];
    const float* be    = (const float*)d_in[5];
    const float* Wroot = (const float*)d_in[6];
    const float* bconv = (const float*)d_in[7];
    const float* gamma = (const float*)d_in[8];
    const float* beta  = (const float*)d_in[9];
    const float* Wlin  = (const float*)d_in[10];
    const float* blin  = (const float*)d_in[11];
    const float* Wq1   = (const float*)d_in[12];
    const float* bq1   = (const float*)d_in[13];
    const float* Wq2   = (const float*)d_in[14];
    const float* bq2   = (const float*)d_in[15];
    float* out = (float*)d_out;

    // workspace layout
    char* ws = (char*)d_ws;
    float* We_t       = (float*)(ws + 0);         //  16 KB
    int*   deg        = (int*)(ws + 16384);       // 200704 B
    int*   cursor     = (int*)(ws + 217088);      // 200704 B
    int*   row_off    = (int*)(ws + 417792);      // 201728 B
    int*   partials   = (int*)(ws + 619520);      // 1 KB
    int*   poff       = (int*)(ws + 620544);      // 1 KB
    float* sorted_msg = (float*)(ws + 621568);    // 25.6 MB

    hipMemsetAsync(deg, 0, 2 * 200704, stream);   // deg + cursor (adjacent)

    transpose_we<<<16, 256, 0, stream>>>(We, We_t);
    hist_kernel<<<(NE + 255) / 256, 256, 0, stream>>>(edst, deg);
    partial_kernel<<<NPART, 256, 0, stream>>>(deg, partials);
    scan_partials_kernel<<<1, 256, 0, stream>>>(partials, poff);
    rowoff_kernel<<<NPART, 256, 0, stream>>>(deg, poff, row_off);
    edge_kernel<<<(NE + 255) / 256, 256, 0, stream>>>(x, esrc, edst, ea, We_t, be,
                                                      row_off, cursor, sorted_msg);
    node_fused_kernel<<<(NN + 63) / 64, 64, 0, stream>>>(x, sorted_msg, row_off,
                                                         Wroot, bconv, gamma, beta,
                                                         Wlin, blin, Wq1, bq1,
                                                         Wq2, bq2, out);
}